// Round 9
// baseline (228.914 us; speedup 1.0000x reference)
//
#include <hip/hip_runtime.h>

// InputDefenseLayer: clip(x, -3.5, 3.5) then EMA scan along T (axis 1):
//   s_0 = xc_0 ; s_t = 0.25*xc_t + 0.75*s_{t-1}
// x: (B=64, T=2048, C=256) float32, contiguous, C innermost.
//
// R10: fill the missing cell of the {waves} x {outstanding} matrix.
//  - Evidence: R6(4096w,32MB)=4.7 TB/s; R7(2048w,16MB)=4.3;
//    R8(4096w,16MB)=4.2; R9(2048w,32MB)=4.3. Neither factor alone
//    recovers R6's rate -> need BOTH: 4 waves/SIMD for stall coverage
//    AND deep per-wave pipelines for request-pool depth.
//  - R10 = L=64 traffic (303 MB, 1.36x amplification) + C-split-2 float2
//    lanes (R8 mapping -> 4096 waves = 4/SIMD) + two-bank PF16 (R9
//    p/q structure, f2 -> 8 KB outstanding/wave -> 32 MB aggregate).
//  - __launch_bounds__(256,4): 4 waves/SIMD requires VGPR <= 128;
//    estimate ~70 (banks 32 + o 16 + addr/temps). No spill expected.
//  - nt loads + nt stores kept (R6's L3-dirty-eviction fix: never
//    allocate -> never evict the reset-fill's dirty lines in-window).
// Numerics: same W=24 seed, same fmaf order -> absmax 0.0078125 unchanged.

constexpr int B = 64;
constexpr int T = 2048;
constexpr int C = 256;
constexpr int L = 64;            // output chunk length along T
constexpr int W = 24;            // warm-up steps: 7*0.75^24 ~ 7e-3 < 7e-2
constexpr int NCHUNK = T / L;    // 32
constexpr int ROWF2 = C / 2;     // 128 float2 per t-row
constexpr int PFD = 16;          // prefetch distance (two 8-row banks)

#define CLIP_LO -3.5f
#define CLIP_HI  3.5f
#define EMA_A 0.25f
#define EMA_B 0.75f

typedef float f2 __attribute__((ext_vector_type(2)));

__device__ __forceinline__ float clipf(float v) {
    return fminf(fmaxf(v, CLIP_LO), CLIP_HI);   // -> v_med3_f32
}

__device__ __forceinline__ f2 clip2(f2 v) {
    f2 r;
    r.x = clipf(v.x);
    r.y = clipf(v.y);
    return r;
}

__device__ __forceinline__ f2 ema2(f2 s, f2 v) {
    f2 r;
    r.x = fmaf(EMA_A, v.x, EMA_B * s.x);
    r.y = fmaf(EMA_A, v.y, EMA_B * s.y);
    return r;
}

// Non-temporal (non-allocating) 8-B load/store.
#define NTLOAD(p)     __builtin_nontemporal_load(p)
#define NTSTORE(v, p) __builtin_nontemporal_store((v), (p))

// Consume row r from named bank register P; re-issue load for row r+PFD
// into the same register. Guards fold at compile time (r, N constants).
#define STEPB(P, r)                                                  \
    {                                                                \
        f2 v = clip2(P);                                             \
        s = ((r) == 0) ? v : ema2(s, v);                             \
        if ((r) + PFD < N) P = NTLOAD(&xp[((r) + PFD) * ROWF2]);     \
    }

// Same, but also latch the state into output register oo (named, static).
#define OSTEPB(P, r, oo)                                             \
    {                                                                \
        f2 v = clip2(P);                                             \
        s = ((r) == 0) ? v : ema2(s, v);                             \
        oo = s;                                                      \
        if ((r) + PFD < N) P = NTLOAD(&xp[((r) + PFD) * ROWF2]);     \
    }

// 8 warm-up rows starting at row r0, consuming bank B0..B7.
#define G8W(Bk, r0)                                                  \
    STEPB(Bk##0, (r0) + 0) STEPB(Bk##1, (r0) + 1)                    \
    STEPB(Bk##2, (r0) + 2) STEPB(Bk##3, (r0) + 3)                    \
    STEPB(Bk##4, (r0) + 4) STEPB(Bk##5, (r0) + 5)                    \
    STEPB(Bk##6, (r0) + 6) STEPB(Bk##7, (r0) + 7)

// 8 output rows starting at r0 from bank Bk (loads-only vmcnt stream),
// then a pinned back-to-back nt store burst of o0..o7.
#define G8S(Bk, r0)                                                  \
    OSTEPB(Bk##0, (r0) + 0, o0) OSTEPB(Bk##1, (r0) + 1, o1)          \
    OSTEPB(Bk##2, (r0) + 2, o2) OSTEPB(Bk##3, (r0) + 3, o3)          \
    OSTEPB(Bk##4, (r0) + 4, o4) OSTEPB(Bk##5, (r0) + 5, o5)          \
    OSTEPB(Bk##6, (r0) + 6, o6) OSTEPB(Bk##7, (r0) + 7, o7)          \
    __builtin_amdgcn_sched_barrier(0);                               \
    NTSTORE(o0, op + ((r0) + 0) * ROWF2);                            \
    NTSTORE(o1, op + ((r0) + 1) * ROWF2);                            \
    NTSTORE(o2, op + ((r0) + 2) * ROWF2);                            \
    NTSTORE(o3, op + ((r0) + 3) * ROWF2);                            \
    NTSTORE(o4, op + ((r0) + 4) * ROWF2);                            \
    NTSTORE(o5, op + ((r0) + 5) * ROWF2);                            \
    NTSTORE(o6, op + ((r0) + 6) * ROWF2);                            \
    NTSTORE(o7, op + ((r0) + 7) * ROWF2);                            \
    __builtin_amdgcn_sched_barrier(0);

// Process rows [0, N): row 0 seeds the EMA state, rows >= SKIP are stored.
// Group g (rows 8g..8g+7) consumes bank g%2 (p even, q odd); prologue
// fills p with rows 0-7 and q with rows 8-15. Reload distance = 16 rows.
template <int N, int SKIP>
__device__ __forceinline__ void run_rows(const f2* __restrict__ xp,
                                         f2* __restrict__ op) {
    f2 p0 = NTLOAD(&xp[0 * ROWF2]);
    f2 p1 = NTLOAD(&xp[1 * ROWF2]);
    f2 p2 = NTLOAD(&xp[2 * ROWF2]);
    f2 p3 = NTLOAD(&xp[3 * ROWF2]);
    f2 p4 = NTLOAD(&xp[4 * ROWF2]);
    f2 p5 = NTLOAD(&xp[5 * ROWF2]);
    f2 p6 = NTLOAD(&xp[6 * ROWF2]);
    f2 p7 = NTLOAD(&xp[7 * ROWF2]);
    f2 q0 = NTLOAD(&xp[8 * ROWF2]);
    f2 q1 = NTLOAD(&xp[9 * ROWF2]);
    f2 q2 = NTLOAD(&xp[10 * ROWF2]);
    f2 q3 = NTLOAD(&xp[11 * ROWF2]);
    f2 q4 = NTLOAD(&xp[12 * ROWF2]);
    f2 q5 = NTLOAD(&xp[13 * ROWF2]);
    f2 q6 = NTLOAD(&xp[14 * ROWF2]);
    f2 q7 = NTLOAD(&xp[15 * ROWF2]);
    f2 s = {};
    f2 o0, o1, o2, o3, o4, o5, o6, o7;

    if constexpr (SKIP == 0) {
        static_assert(N == L, "k==0 path is 64 rows");
        G8S(p, 0)
        G8S(q, 8)
        G8S(p, 16)
        G8S(q, 24)
        G8S(p, 32)
        G8S(q, 40)
        G8S(p, 48)
        G8S(q, 56)
    } else {
        static_assert(SKIP == W && N == W + L, "warm-up path is 24+64 rows");
        G8W(p, 0)
        G8W(q, 8)
        G8W(p, 16)
        G8S(q, 24)
        G8S(p, 32)
        G8S(q, 40)
        G8S(p, 48)
        G8S(q, 56)
        G8S(p, 64)
        G8S(q, 72)
        G8S(p, 80)
    }
}

__global__ __launch_bounds__(256, 4) void ema_kernel(
    const float* __restrict__ x, float* __restrict__ out)
{
    // 4 jobs per 256-thread block; each job = one wave = half a chunk's C.
    const int job  = blockIdx.x * 4 + (threadIdx.x >> 6);
    const int lane = threadIdx.x & 63;
    const int half = job & 1;             // which C-half this wave owns
    const int chnk = job >> 1;            // chunk id: 0 .. B*NCHUNK-1
    const int b    = chnk >> 5;           // / NCHUNK (32)
    const int k    = chnk & (NCHUNK - 1); // % NCHUNK
    const int t0   = k * L;
    const int tb   = (k == 0) ? 0 : (t0 - W);

    const f2* __restrict__ xp =
        (const f2*)x + ((size_t)b * T + tb) * ROWF2 + half * 64 + lane;
    f2* __restrict__ op =
        (f2*)out     + ((size_t)b * T + tb) * ROWF2 + half * 64 + lane;

    if (k == 0) {
        run_rows<L, 0>(xp, op);           // exact from t=0, store all 64 rows
    } else {
        run_rows<W + L, W>(xp, op);       // 24 warm-up rows, store last 64
    }
}

extern "C" void kernel_launch(void* const* d_in, const int* in_sizes, int n_in,
                              void* d_out, int out_size, void* d_ws, size_t ws_size,
                              hipStream_t stream) {
    const float* x = (const float*)d_in[0];
    float* out = (float*)d_out;
    const int n_jobs = B * NCHUNK * 2;             // 4096
    ema_kernel<<<dim3(n_jobs / 4), dim3(256), 0, stream>>>(x, out);
}

// Round 10
// 227.514 us; speedup vs baseline: 1.0062x; 1.0062x over previous
//
#include <hip/hip_runtime.h>

// InputDefenseLayer: clip(x, -3.5, 3.5) then EMA scan along T (axis 1):
//   s_0 = xc_0 ; s_t = 0.25*xc_t + 0.75*s_{t-1}
// x: (B=64, T=2048, C=256) float32, contiguous, C innermost.
//
// R11: traffic knob, last notch. L 64 -> 128.
//  - R7-R10 completed the {waves} x {outstanding} matrix: rate is
//    ~4.2-4.4 TB/s in the non-allocating regime REGARDLESS of geometry
//    (R6's apparent 4.7 = estimation slop). Rate is exhausted as a lever.
//  - The only reliably-positive lever was traffic (R6->R7: 350->303 MB).
//    L=128: amplification (128+15*152)/2048 = 1.176x -> ~278 MB total
//    (FETCH ~150 MB + WRITE 128 MB). Projected ema ~64.7 us @ 4.3 TB/s.
//  - Geometry stays inside the measured-rate envelope: C-split-2 float2
//    lanes (2048 waves = 2/SIMD, R7/R9 corner) + two-bank PF16
//    (8 KB outstanding/wave). VGPR ~64, no spill.
//  - nt loads + nt stores kept (R6's L3-dirty-eviction fix: never
//    allocate -> never evict the reset-fill's dirty lines in-window).
// Numerics: W=24 seed, same fmaf order as R1-R10 -> absmax 0.0078125.

constexpr int B = 64;
constexpr int T = 2048;
constexpr int C = 256;
constexpr int L = 128;           // output chunk length along T (R11: was 64)
constexpr int W = 24;            // warm-up steps: 7*0.75^24 ~ 7e-3 < 7e-2
constexpr int NCHUNK = T / L;    // 16
constexpr int ROWF2 = C / 2;     // 128 float2 per t-row
constexpr int PFD = 16;          // prefetch distance (two 8-row banks)

#define CLIP_LO -3.5f
#define CLIP_HI  3.5f
#define EMA_A 0.25f
#define EMA_B 0.75f

typedef float f2 __attribute__((ext_vector_type(2)));

__device__ __forceinline__ float clipf(float v) {
    return fminf(fmaxf(v, CLIP_LO), CLIP_HI);   // -> v_med3_f32
}

__device__ __forceinline__ f2 clip2(f2 v) {
    f2 r;
    r.x = clipf(v.x);
    r.y = clipf(v.y);
    return r;
}

__device__ __forceinline__ f2 ema2(f2 s, f2 v) {
    f2 r;
    r.x = fmaf(EMA_A, v.x, EMA_B * s.x);
    r.y = fmaf(EMA_A, v.y, EMA_B * s.y);
    return r;
}

// Non-temporal (non-allocating) 8-B load/store.
#define NTLOAD(p)     __builtin_nontemporal_load(p)
#define NTSTORE(v, p) __builtin_nontemporal_store((v), (p))

// Consume row r from named bank register P; re-issue load for row r+PFD
// into the same register. Guards fold at compile time (r, N constants).
#define STEPB(P, r)                                                  \
    {                                                                \
        f2 v = clip2(P);                                             \
        s = ((r) == 0) ? v : ema2(s, v);                             \
        if ((r) + PFD < N) P = NTLOAD(&xp[((r) + PFD) * ROWF2]);     \
    }

// Same, but also latch the state into output register oo (named, static).
#define OSTEPB(P, r, oo)                                             \
    {                                                                \
        f2 v = clip2(P);                                             \
        s = ((r) == 0) ? v : ema2(s, v);                             \
        oo = s;                                                      \
        if ((r) + PFD < N) P = NTLOAD(&xp[((r) + PFD) * ROWF2]);     \
    }

// 8 warm-up rows starting at row r0, consuming bank Bk0..Bk7.
#define G8W(Bk, r0)                                                  \
    STEPB(Bk##0, (r0) + 0) STEPB(Bk##1, (r0) + 1)                    \
    STEPB(Bk##2, (r0) + 2) STEPB(Bk##3, (r0) + 3)                    \
    STEPB(Bk##4, (r0) + 4) STEPB(Bk##5, (r0) + 5)                    \
    STEPB(Bk##6, (r0) + 6) STEPB(Bk##7, (r0) + 7)

// 8 output rows starting at r0 from bank Bk (loads-only vmcnt stream),
// then a pinned back-to-back nt store burst of o0..o7.
#define G8S(Bk, r0)                                                  \
    OSTEPB(Bk##0, (r0) + 0, o0) OSTEPB(Bk##1, (r0) + 1, o1)          \
    OSTEPB(Bk##2, (r0) + 2, o2) OSTEPB(Bk##3, (r0) + 3, o3)          \
    OSTEPB(Bk##4, (r0) + 4, o4) OSTEPB(Bk##5, (r0) + 5, o5)          \
    OSTEPB(Bk##6, (r0) + 6, o6) OSTEPB(Bk##7, (r0) + 7, o7)          \
    __builtin_amdgcn_sched_barrier(0);                               \
    NTSTORE(o0, op + ((r0) + 0) * ROWF2);                            \
    NTSTORE(o1, op + ((r0) + 1) * ROWF2);                            \
    NTSTORE(o2, op + ((r0) + 2) * ROWF2);                            \
    NTSTORE(o3, op + ((r0) + 3) * ROWF2);                            \
    NTSTORE(o4, op + ((r0) + 4) * ROWF2);                            \
    NTSTORE(o5, op + ((r0) + 5) * ROWF2);                            \
    NTSTORE(o6, op + ((r0) + 6) * ROWF2);                            \
    NTSTORE(o7, op + ((r0) + 7) * ROWF2);                            \
    __builtin_amdgcn_sched_barrier(0);

// Process rows [0, N): row 0 seeds the EMA state, rows >= SKIP are stored.
// Group g (rows 8g..8g+7) consumes bank g%2 (p even, q odd); prologue
// fills p with rows 0-7 and q with rows 8-15. Reload distance = 16 rows.
template <int N, int SKIP>
__device__ __forceinline__ void run_rows(const f2* __restrict__ xp,
                                         f2* __restrict__ op) {
    f2 p0 = NTLOAD(&xp[0 * ROWF2]);
    f2 p1 = NTLOAD(&xp[1 * ROWF2]);
    f2 p2 = NTLOAD(&xp[2 * ROWF2]);
    f2 p3 = NTLOAD(&xp[3 * ROWF2]);
    f2 p4 = NTLOAD(&xp[4 * ROWF2]);
    f2 p5 = NTLOAD(&xp[5 * ROWF2]);
    f2 p6 = NTLOAD(&xp[6 * ROWF2]);
    f2 p7 = NTLOAD(&xp[7 * ROWF2]);
    f2 q0 = NTLOAD(&xp[8 * ROWF2]);
    f2 q1 = NTLOAD(&xp[9 * ROWF2]);
    f2 q2 = NTLOAD(&xp[10 * ROWF2]);
    f2 q3 = NTLOAD(&xp[11 * ROWF2]);
    f2 q4 = NTLOAD(&xp[12 * ROWF2]);
    f2 q5 = NTLOAD(&xp[13 * ROWF2]);
    f2 q6 = NTLOAD(&xp[14 * ROWF2]);
    f2 q7 = NTLOAD(&xp[15 * ROWF2]);
    f2 s = {};
    f2 o0, o1, o2, o3, o4, o5, o6, o7;

    if constexpr (SKIP == 0) {
        static_assert(N == L, "k==0 path is 128 rows");
        G8S(p, 0)   G8S(q, 8)   G8S(p, 16)  G8S(q, 24)
        G8S(p, 32)  G8S(q, 40)  G8S(p, 48)  G8S(q, 56)
        G8S(p, 64)  G8S(q, 72)  G8S(p, 80)  G8S(q, 88)
        G8S(p, 96)  G8S(q, 104) G8S(p, 112) G8S(q, 120)
    } else {
        static_assert(SKIP == W && N == W + L, "warm-up path is 24+128 rows");
        G8W(p, 0)   G8W(q, 8)   G8W(p, 16)
        G8S(q, 24)  G8S(p, 32)  G8S(q, 40)  G8S(p, 48)
        G8S(q, 56)  G8S(p, 64)  G8S(q, 72)  G8S(p, 80)
        G8S(q, 88)  G8S(p, 96)  G8S(q, 104) G8S(p, 112)
        G8S(q, 120) G8S(p, 128) G8S(q, 136) G8S(p, 144)
    }
}

__global__ __launch_bounds__(256, 2) void ema_kernel(
    const float* __restrict__ x, float* __restrict__ out)
{
    // 4 jobs per 256-thread block; each job = one wave = half a chunk's C.
    const int job  = blockIdx.x * 4 + (threadIdx.x >> 6);
    const int lane = threadIdx.x & 63;
    const int half = job & 1;             // which C-half this wave owns
    const int chnk = job >> 1;            // chunk id: 0 .. B*NCHUNK-1
    const int b    = chnk >> 4;           // / NCHUNK (16)
    const int k    = chnk & (NCHUNK - 1); // % NCHUNK
    const int t0   = k * L;
    const int tb   = (k == 0) ? 0 : (t0 - W);

    const f2* __restrict__ xp =
        (const f2*)x + ((size_t)b * T + tb) * ROWF2 + half * 64 + lane;
    f2* __restrict__ op =
        (f2*)out     + ((size_t)b * T + tb) * ROWF2 + half * 64 + lane;

    if (k == 0) {
        run_rows<L, 0>(xp, op);           // exact from t=0, store all 128 rows
    } else {
        run_rows<W + L, W>(xp, op);       // 24 warm-up rows, store last 128
    }
}

extern "C" void kernel_launch(void* const* d_in, const int* in_sizes, int n_in,
                              void* d_out, int out_size, void* d_ws, size_t ws_size,
                              hipStream_t stream) {
    const float* x = (const float*)d_in[0];
    float* out = (float*)d_out;
    const int n_jobs = B * NCHUNK * 2;             // 2048
    ema_kernel<<<dim3(n_jobs / 4), dim3(256), 0, stream>>>(x, out);
}